// Round 2
// baseline (7520.433 us; speedup 1.0000x reference)
//
#include <hip/hip_runtime.h>
#include <hip/hip_bf16.h>
#include <cstdint>
#include <cstddef>

typedef __hip_bfloat16 bf16;
typedef float  f32x4   __attribute__((ext_vector_type(4)));
typedef float  float4v __attribute__((ext_vector_type(4)));
typedef short  short8  __attribute__((ext_vector_type(8)));
typedef short  short4v __attribute__((ext_vector_type(4)));
typedef __bf16 bf16x8  __attribute__((ext_vector_type(8)));

__device__ __forceinline__ void mfma16(f32x4& d, short8 a, short8 b) {
  d = __builtin_amdgcn_mfma_f32_16x16x32_bf16(
      __builtin_bit_cast(bf16x8, a), __builtin_bit_cast(bf16x8, b), d, 0, 0, 0);
}
__device__ __forceinline__ unsigned short f2b_bits(float x) {
  __hip_bfloat16 h = __float2bfloat16(x);
  return __builtin_bit_cast(unsigned short, h);
}
__device__ __forceinline__ float gelu_exact(float x) {
  return 0.5f * x * (1.0f + erff(x * 0.7071067811865475f));
}

// ---------- f32 -> bf16 convert, 4 elems/thread ----------
__global__ __launch_bounds__(256) void k_cvt(const float* __restrict__ src,
                                             bf16* __restrict__ dst, int n4) {
  int i = blockIdx.x * 256 + threadIdx.x;
  if (i >= n4) return;
  float4v v = *(const float4v*)(src + (size_t)i * 4);
  short4v s;
  s[0] = (short)f2b_bits(v[0]); s[1] = (short)f2b_bits(v[1]);
  s[2] = (short)f2b_bits(v[2]); s[3] = (short)f2b_bits(v[3]);
  *(short4v*)((short*)dst + (size_t)i * 4) = s;
}

// ---------- transpose (+optional per-k scale): f32 (K,N) -> bf16 (N,K) ----------
__global__ void k_tfold(const float* __restrict__ src, const float* __restrict__ scale,
                        bf16* __restrict__ dst, int K, int N,
                        long long src_bs, long long scale_bs, long long dst_bs) {
  src += (size_t)blockIdx.z * src_bs;
  dst += (size_t)blockIdx.z * dst_bs;
  const float* sc = scale ? scale + (size_t)blockIdx.z * scale_bs : nullptr;
  __shared__ float tile[32][33];
  int n0 = blockIdx.x * 32, k0 = blockIdx.y * 32;
  int tx = threadIdx.x, ty = threadIdx.y;
#pragma unroll
  for (int j = 0; j < 4; ++j) {
    int k = k0 + ty + j * 8;
    float s = sc ? sc[k] : 1.0f;
    tile[ty + j * 8][tx] = src[(size_t)k * N + n0 + tx] * s;
  }
  __syncthreads();
#pragma unroll
  for (int j = 0; j < 4; ++j) {
    int n = n0 + ty + j * 8;
    dst[(size_t)n * K + k0 + tx] = __float2bfloat16(tile[tx][ty + j * 8]);
  }
}

// ---------- bias fold: out[n] = sum_k lnb[k]*W[k][n] ----------
__global__ __launch_bounds__(256) void k_bfold(const float* __restrict__ W,
                                               const float* __restrict__ lnb,
                                               float* __restrict__ out, int K, int N,
                                               long long w_bs, long long b_bs, long long o_bs) {
  W   += (size_t)blockIdx.y * w_bs;
  lnb += (size_t)blockIdx.y * b_bs;
  out += (size_t)blockIdx.y * o_bs;
  int n = blockIdx.x * 256 + threadIdx.x;
  float a = 0.0f;
  for (int k = 0; k < K; ++k) a = fmaf(lnb[k], W[(size_t)k * N + n], a);
  out[n] = a;
}

// ---------- row standardize (768-wide), f32 -> bf16 ----------
__global__ __launch_bounds__(256) void k_std(const float* __restrict__ src,
                                             bf16* __restrict__ dst) {
  int row = blockIdx.x;
  const float* x = src + (size_t)row * 768;
  int t = threadIdx.x;
  float a0 = x[t], a1 = x[t + 256], a2 = x[t + 512];
  float s = a0 + a1 + a2;
  float q = a0 * a0 + a1 * a1 + a2 * a2;
#pragma unroll
  for (int off = 1; off < 64; off <<= 1) { s += __shfl_xor(s, off); q += __shfl_xor(q, off); }
  __shared__ float ss[4], qs[4];
  if ((t & 63) == 0) { ss[t >> 6] = s; qs[t >> 6] = q; }
  __syncthreads();
  s = ss[0] + ss[1] + ss[2] + ss[3];
  q = qs[0] + qs[1] + qs[2] + qs[3];
  float mean = s * (1.0f / 768.0f);
  float var  = q * (1.0f / 768.0f) - mean * mean;
  float inv  = rsqrtf(var + 1e-5f);
  bf16* d = dst + (size_t)row * 768;
  d[t]       = __float2bfloat16((a0 - mean) * inv);
  d[t + 256] = __float2bfloat16((a1 - mean) * inv);
  d[t + 512] = __float2bfloat16((a2 - mean) * inv);
}

// ---------- final layernorm (768-wide) with w,b: f32 -> f32 ----------
__global__ __launch_bounds__(256) void k_lnout(const float* __restrict__ src,
                                               const float* __restrict__ w,
                                               const float* __restrict__ b,
                                               float* __restrict__ dst) {
  int row = blockIdx.x;
  const float* x = src + (size_t)row * 768;
  int t = threadIdx.x;
  float a0 = x[t], a1 = x[t + 256], a2 = x[t + 512];
  float s = a0 + a1 + a2;
  float q = a0 * a0 + a1 * a1 + a2 * a2;
#pragma unroll
  for (int off = 1; off < 64; off <<= 1) { s += __shfl_xor(s, off); q += __shfl_xor(q, off); }
  __shared__ float ss[4], qs[4];
  if ((t & 63) == 0) { ss[t >> 6] = s; qs[t >> 6] = q; }
  __syncthreads();
  s = ss[0] + ss[1] + ss[2] + ss[3];
  q = qs[0] + qs[1] + qs[2] + qs[3];
  float mean = s * (1.0f / 768.0f);
  float var  = q * (1.0f / 768.0f) - mean * mean;
  float inv  = rsqrtf(var + 1e-5f);
  float* d = dst + (size_t)row * 768;
  d[t]       = (a0 - mean) * inv * w[t]       + b[t];
  d[t + 256] = (a1 - mean) * inv * w[t + 256] + b[t + 256];
  d[t + 512] = (a2 - mean) * inv * w[t + 512] + b[t + 512];
}

// ---------- MFMA GEMM: C(M,N) = A(M,K)bf16 @ Bt(N,K)bf16 [+bias][gelu][+res f32] ----------
template <int BM, int BN, bool OBF16, bool GELU>
__global__ __launch_bounds__(256) void k_gemm(const bf16* __restrict__ A,
                                              const bf16* __restrict__ Bt,
                                              void* __restrict__ Cv,
                                              const float* __restrict__ bias,
                                              const float* __restrict__ res,
                                              int M, int N, int K) {
  constexpr int AI = BM / 32, BI = BN / 32;
  constexpr int MF = BM / 32, NF = BN / 32;
  __shared__ __align__(16) char As[BM * 128];
  __shared__ __align__(16) char Bs[BN * 128];
  const int bm = blockIdx.x * BM, bn = blockIdx.y * BN;
  const int t = threadIdx.x, lane = t & 63, w = t >> 6;
  const int wr = w >> 1, wc = w & 1;
  const int l15 = lane & 15, lg = lane >> 4;
  const int srow = t >> 3, scol = t & 7;

  const bf16* aptr[AI]; int aoff[AI];
#pragma unroll
  for (int i = 0; i < AI; ++i) {
    int r = i * 32 + srow;
    int gr = bm + r; if (gr > M - 1) gr = M - 1;
    aptr[i] = A + (size_t)gr * K + scol * 8;
    aoff[i] = r * 128 + ((scol * 16) ^ ((r & 7) << 4));
  }
  const bf16* bptr[BI]; int boff[BI];
#pragma unroll
  for (int i = 0; i < BI; ++i) {
    int r = i * 32 + srow;
    int gc = bn + r; if (gc > N - 1) gc = N - 1;
    bptr[i] = Bt + (size_t)gc * K + scol * 8;
    boff[i] = r * 128 + ((scol * 16) ^ ((r & 7) << 4));
  }

  f32x4 acc[MF][NF] = {};
  short8 av[AI], bv[BI];
#pragma unroll
  for (int i = 0; i < AI; ++i) av[i] = *(const short8*)(aptr[i]);
#pragma unroll
  for (int i = 0; i < BI; ++i) bv[i] = *(const short8*)(bptr[i]);

  const int nk = K / 64;
  for (int kt = 0; kt < nk; ++kt) {
    __syncthreads();
#pragma unroll
    for (int i = 0; i < AI; ++i) *(short8*)(As + aoff[i]) = av[i];
#pragma unroll
    for (int i = 0; i < BI; ++i) *(short8*)(Bs + boff[i]) = bv[i];
    __syncthreads();
    if (kt + 1 < nk) {
#pragma unroll
      for (int i = 0; i < AI; ++i) av[i] = *(const short8*)(aptr[i] + (size_t)(kt + 1) * 64);
#pragma unroll
      for (int i = 0; i < BI; ++i) bv[i] = *(const short8*)(bptr[i] + (size_t)(kt + 1) * 64);
    }
#pragma unroll
    for (int ks = 0; ks < 2; ++ks) {
      short8 af[MF], bfr[NF];
#pragma unroll
      for (int m = 0; m < MF; ++m) {
        int r = wr * (BM / 2) + m * 16 + l15;
        af[m] = *(const short8*)(As + r * 128 + ((ks * 64 + lg * 16) ^ ((r & 7) << 4)));
      }
#pragma unroll
      for (int n = 0; n < NF; ++n) {
        int r = wc * (BN / 2) + n * 16 + l15;
        bfr[n] = *(const short8*)(Bs + r * 128 + ((ks * 64 + lg * 16) ^ ((r & 7) << 4)));
      }
#pragma unroll
      for (int m = 0; m < MF; ++m)
#pragma unroll
        for (int n = 0; n < NF; ++n) mfma16(acc[m][n], af[m], bfr[n]);
    }
  }
#pragma unroll
  for (int m = 0; m < MF; ++m) {
    int gr0 = bm + wr * (BM / 2) + m * 16 + lg * 4;
#pragma unroll
    for (int n = 0; n < NF; ++n) {
      int gc = bn + wc * (BN / 2) + n * 16 + l15;
      float bvs = bias ? bias[gc] : 0.0f;
#pragma unroll
      for (int r = 0; r < 4; ++r) {
        int gr = gr0 + r;
        if (gr < M) {
          float v = acc[m][n][r] + bvs;
          if (GELU) v = gelu_exact(v);
          if (res) v += res[(size_t)gr * N + gc];
          if (OBF16) ((bf16*)Cv)[(size_t)gr * N + gc] = __float2bfloat16(v);
          else       ((float*)Cv)[(size_t)gr * N + gc] = v;
        }
      }
    }
  }
}

// ---------- fused attention: one block per (local b, h); 4 waves, 16 q-rows each ----------
// qkvl: (B*64, 3072) = [q | k_lat | v_lat] (global batch); kvx: (bc*n1, 2048) local chunk
__global__ __launch_bounds__(256) void k_attn(const bf16* __restrict__ qkvl,
                                              const bf16* __restrict__ kvx,
                                              bf16* __restrict__ outp, int n1, int b0) {
  const int bh = blockIdx.x;
  const int bl = bh >> 4, h = bh & 15;
  const int b = b0 + bl;
  __shared__ __align__(16) char Qs[64 * 128];
  __shared__ __align__(16) char Ks[64 * 128];
  __shared__ __align__(16) char Vt[64 * 128];
  __shared__ __align__(16) char Ps[4][16 * 128];
  const int t = threadIdx.x, lane = t & 63, w = t >> 6;
  const int l15 = lane & 15, lg = lane >> 4;

#pragma unroll
  for (int it = 0; it < 2; ++it) {
    int slot = it * 256 + t; int r = slot >> 3, c = slot & 7;
    short8 v = *(const short8*)(qkvl + (size_t)(b * 64 + r) * 3072 + h * 64 + c * 8);
    *(short8*)(Qs + r * 128 + ((c * 16) ^ ((r & 7) << 4))) = v;
  }
  const int n_kv = n1 + 64;
  const int nch = (n_kv + 63) >> 6;
  float m_run[4], l_run[4];
  f32x4 o[4] = {};
#pragma unroll
  for (int r = 0; r < 4; ++r) { m_run[r] = -1e30f; l_run[r] = 0.0f; }

  short8 kreg[2], vreg[2];
  auto loadKV = [&](int ch) {
#pragma unroll
    for (int it = 0; it < 2; ++it) {
      int slot = it * 256 + t; int rr = slot >> 3, c = slot & 7;
      int j = ch * 64 + rr;
      short8 kv = {}; short8 vv = {};
      if (j < n_kv) {
        const bf16* kb;
        if (j < n1) kb = kvx + (size_t)(bl * n1 + j) * 2048 + h * 64;
        else        kb = qkvl + (size_t)(b * 64 + (j - n1)) * 3072 + 1024 + h * 64;
        kv = *(const short8*)(kb + c * 8);
        vv = *(const short8*)(kb + 1024 + c * 8);
      }
      kreg[it] = kv; vreg[it] = vv;
    }
  };
  loadKV(0);

  for (int ch = 0; ch < nch; ++ch) {
    __syncthreads();
#pragma unroll
    for (int it = 0; it < 2; ++it) {
      int slot = it * 256 + t; int rr = slot >> 3, c = slot & 7;
      *(short8*)(Ks + rr * 128 + ((c * 16) ^ ((rr & 7) << 4))) = kreg[it];
#pragma unroll
      for (int j2 = 0; j2 < 8; ++j2) {
        int dh = c * 8 + j2;
        *(short*)(Vt + dh * 128 + ((rr * 2) ^ ((dh & 7) << 4))) = vreg[it][j2];
      }
    }
    __syncthreads();
    if (ch + 1 < nch) loadKV(ch + 1);

    f32x4 s[4] = {};
#pragma unroll
    for (int ks = 0; ks < 2; ++ks) {
      int qr = w * 16 + l15;
      short8 qf = *(const short8*)(Qs + qr * 128 + ((ks * 64 + lg * 16) ^ ((qr & 7) << 4)));
#pragma unroll
      for (int n = 0; n < 4; ++n) {
        int kr = n * 16 + l15;
        short8 kf = *(const short8*)(Ks + kr * 128 + ((ks * 64 + lg * 16) ^ ((kr & 7) << 4)));
        mfma16(s[n], qf, kf);
      }
    }
    float p[4][4];
#pragma unroll
    for (int r = 0; r < 4; ++r) {
      float mx = m_run[r];
#pragma unroll
      for (int n = 0; n < 4; ++n) {
        float v = s[n][r] * 0.125f;
        int kvi = ch * 64 + n * 16 + l15;
        if (kvi >= n_kv) v = -1e30f;
        s[n][r] = v;
        mx = fmaxf(mx, v);
      }
#pragma unroll
      for (int off = 1; off < 16; off <<= 1) mx = fmaxf(mx, __shfl_xor(mx, off));
      float scl = __expf(m_run[r] - mx);
      m_run[r] = mx;
      float rs = 0.0f;
#pragma unroll
      for (int n = 0; n < 4; ++n) { float pv = __expf(s[n][r] - mx); p[n][r] = pv; rs += pv; }
#pragma unroll
      for (int off = 1; off < 16; off <<= 1) rs += __shfl_xor(rs, off);
      l_run[r] = l_run[r] * scl + rs;
#pragma unroll
      for (int nn = 0; nn < 4; ++nn) o[nn][r] *= scl;
    }
#pragma unroll
    for (int n = 0; n < 4; ++n)
#pragma unroll
      for (int r = 0; r < 4; ++r) {
        int q = lg * 4 + r; int kv = n * 16 + l15;
        *(unsigned short*)(Ps[w] + q * 128 + ((kv * 2) ^ ((q & 7) << 4))) = f2b_bits(p[n][r]);
      }
#pragma unroll
    for (int ks = 0; ks < 2; ++ks) {
      short8 pf = *(const short8*)(Ps[w] + l15 * 128 + ((ks * 64 + lg * 16) ^ ((l15 & 7) << 4)));
#pragma unroll
      for (int nn = 0; nn < 4; ++nn) {
        int dh = nn * 16 + l15;
        short8 vf = *(const short8*)(Vt + dh * 128 + ((ks * 64 + lg * 16) ^ ((dh & 7) << 4)));
        mfma16(o[nn], pf, vf);
      }
    }
  }
#pragma unroll
  for (int nn = 0; nn < 4; ++nn)
#pragma unroll
    for (int r = 0; r < 4; ++r) {
      int qr = w * 16 + lg * 4 + r;
      int dh = nn * 16 + l15;
      float v = o[nn][r] / l_run[r];
      outp[(size_t)(b * 64 + qr) * 1024 + h * 64 + dh] = __float2bfloat16(v);
    }
}

// =========================== host ===========================
extern "C" void kernel_launch(void* const* d_in, const int* in_sizes, int n_in,
                              void* d_out, int out_size, void* d_ws, size_t ws_size,
                              hipStream_t stream) {
  (void)in_sizes; (void)n_in; (void)out_size;
  const float* id_emb = (const float*)d_in[0];
  const float* f_in[4]  = {(const float*)d_in[4],  (const float*)d_in[3],
                           (const float*)d_in[2],  (const float*)d_in[1]};
  const float* pw_in[4] = {(const float*)d_in[11], (const float*)d_in[9],
                           (const float*)d_in[7],  (const float*)d_in[5]};
  const float* pb_in[4] = {(const float*)d_in[12], (const float*)d_in[10],
                           (const float*)d_in[8],  (const float*)d_in[6]};
  const float* ln1w = (const float*)d_in[13];
  const float* ln1b = (const float*)d_in[14];
  const float* ln2w = (const float*)d_in[15];
  const float* ln2b = (const float*)d_in[16];
  const float* wq   = (const float*)d_in[17];
  const float* wkv  = (const float*)d_in[18];
  const float* wo   = (const float*)d_in[19];
  const float* fflnw = (const float*)d_in[20];
  const float* fflnb = (const float*)d_in[21];
  const float* ffw1  = (const float*)d_in[22];
  const float* ffw2  = (const float*)d_in[23];
  const float* projw = (const float*)d_in[24];
  const float* projb = (const float*)d_in[25];
  const float* normw = (const float*)d_in[26];
  const float* normb = (const float*)d_in[27];

  static const int N1S[4]  = {49, 196, 784, 3136};
  static const int FRDS[4] = {512, 256, 128, 64};

  // ---- adaptive workspace plan (ws_size is fixed per run -> deterministic) ----
  bf16 *zfeat[4], *fbf[4], *pT[4], *projT;
  float *qkvl_bias, *kvx_bias, *ff_bias, *lat, *headtmp;
  bf16 *qkvl_act, *attnout, *zlat, *latbf, *ffh;
  bf16 *wqkvlT = nullptr, *wkvxT = nullptr, *woT = nullptr, *w1T = nullptr, *w2T = nullptr;
  bf16 *wbuf = nullptr;
  char *big;

  auto assign = [&](bool fullw, int bc) -> size_t {
    size_t off = 0; char* base = (char*)d_ws;
    auto A = [&](size_t b) -> char* {
      char* p = base + off; off = (off + b + 255) & ~(size_t)255; return p;
    };
    for (int i = 0; i < 4; ++i) zfeat[i] = (bf16*)A((size_t)16 * N1S[i] * 768 * 2);
    for (int i = 0; i < 4; ++i) fbf[i]   = (bf16*)A((size_t)16 * N1S[i] * FRDS[i] * 2);
    for (int i = 0; i < 4; ++i) pT[i]    = (bf16*)A((size_t)768 * FRDS[i] * 2);
    projT     = (bf16*)A(768ull * 768 * 2);
    qkvl_bias = (float*)A(24ull * 3072 * 4);
    kvx_bias  = (float*)A(24ull * 2048 * 4);
    ff_bias   = (float*)A(6ull * 3072 * 4);
    qkvl_act  = (bf16*)A(1024ull * 3072 * 2);
    attnout   = (bf16*)A(1024ull * 1024 * 2);
    lat       = (float*)A(1024ull * 768 * 4);
    zlat      = (bf16*)A(1024ull * 768 * 2);
    if (fullw) {
      wqkvlT = (bf16*)A(24ull * 3072 * 768 * 2);
      wkvxT  = (bf16*)A(24ull * 2048 * 768 * 2);
      woT    = (bf16*)A(24ull * 768 * 1024 * 2);
      w1T    = (bf16*)A(6ull * 3072 * 768 * 2);
      w2T    = (bf16*)A(6ull * 768 * 3072 * 2);
      wbuf = nullptr;
    } else {
      wbuf = (bf16*)A(((3072ull + 2048) * 768 + 768ull * 1024) * 2);
      wqkvlT = wkvxT = woT = w1T = w2T = nullptr;
    }
    big = A((size_t)bc * 3136 * 2048 * 2);
    ffh = qkvl_act; headtmp = (float*)qkvl_act; latbf = zlat;
    return off;
  };

  static const bool FULLS[10] = {true,true,true,false,false,true,true,false,false,false};
  static const int  BCS[10]   = {16,  8,   4,   16,   8,    2,   1,   4,    2,    1};
  bool fullw = false; int bc = 1; bool ok = false;
  for (int c = 0; c < 10; ++c) {
    if (assign(FULLS[c], BCS[c]) <= ws_size) { fullw = FULLS[c]; bc = BCS[c]; ok = true; break; }
  }
  if (!ok) return;

  float* featf32 = (float*)big;
  bf16*  kvxbuf  = (bf16*)big;

  auto gemm = [&](int tile, const bf16* A, const bf16* Bt, void* C,
                  const float* bias, const float* res, int M, int N, int K,
                  bool obf, bool gl) {
    if (tile == 128) {
      dim3 g((M + 127) / 128, N / 128);
      if (obf && gl) k_gemm<128,128,true ,true ><<<g,256,0,stream>>>(A,Bt,C,bias,res,M,N,K);
      else if (obf)  k_gemm<128,128,true ,false><<<g,256,0,stream>>>(A,Bt,C,bias,res,M,N,K);
      else           k_gemm<128,128,false,false><<<g,256,0,stream>>>(A,Bt,C,bias,res,M,N,K);
    } else {
      dim3 g((M + 63) / 64, N / 64);
      if (obf)       k_gemm<64,64,true ,false><<<g,256,0,stream>>>(A,Bt,C,bias,res,M,N,K);
      else           k_gemm<64,64,false,false><<<g,256,0,stream>>>(A,Bt,C,bias,res,M,N,K);
    }
  };

  dim3 tb(32, 8);

  // ---- bias folds (all layers, upfront; tiny outputs) ----
  k_bfold<<<dim3(4, 24), 256, 0, stream>>>(wq,  ln2b, qkvl_bias,        768, 1024, 768LL*1024, 768, 3072);
  k_bfold<<<dim3(8, 24), 256, 0, stream>>>(wkv, ln2b, qkvl_bias + 1024, 768, 2048, 768LL*2048, 768, 3072);
  k_bfold<<<dim3(8, 24), 256, 0, stream>>>(wkv, ln1b, kvx_bias,         768, 2048, 768LL*2048, 768, 2048);
  k_bfold<<<dim3(12, 6), 256, 0, stream>>>(ffw1, fflnb, ff_bias,        768, 3072, 768LL*3072, 768, 3072);

  // ---- small folded weights (always) ----
  for (int i = 0; i < 4; ++i)
    k_tfold<<<dim3(24, FRDS[i] / 32, 1), tb, 0, stream>>>(pw_in[i], nullptr, pT[i], FRDS[i], 768, 0, 0, 0);
  k_tfold<<<dim3(24, 24, 1), tb, 0, stream>>>(projw, nullptr, projT, 768, 768, 0, 0, 0);

  // ---- full-mode weight folds (batched over layers) ----
  if (fullw) {
    k_tfold<<<dim3(32, 24, 24), tb, 0, stream>>>(wq,  ln2w, wqkvlT,              768, 1024, 768LL*1024, 768, 3072LL*768);
    k_tfold<<<dim3(64, 24, 24), tb, 0, stream>>>(wkv, ln2w, wqkvlT + 1024LL*768, 768, 2048, 768LL*2048, 768, 3072LL*768);
    k_tfold<<<dim3(64, 24, 24), tb, 0, stream>>>(wkv, ln1w, wkvxT,               768, 2048, 768LL*2048, 768, 2048LL*768);
    k_tfold<<<dim3(24, 32, 24), tb, 0, stream>>>(wo,  nullptr, woT,             1024,  768, 1024LL*768,   0,  768LL*1024);
    k_tfold<<<dim3(96, 24, 6),  tb, 0, stream>>>(ffw1, fflnw, w1T,               768, 3072, 768LL*3072, 768, 3072LL*768);
    k_tfold<<<dim3(24, 96, 6),  tb, 0, stream>>>(ffw2, nullptr, w2T,            3072,  768, 3072LL*768,   0,  768LL*3072);
  }

  auto attnW = [&](int di, const bf16*& qkvlT_p, const bf16*& kvxT_p, const bf16*& woT_p) {
    if (fullw) {
      qkvlT_p = wqkvlT + (size_t)di * 3072 * 768;
      kvxT_p  = wkvxT  + (size_t)di * 2048 * 768;
      woT_p   = woT    + (size_t)di * 768 * 1024;
    } else {
      bf16* dq   = wbuf;
      bf16* dkvx = wbuf + 3072ull * 768;
      bf16* dwo  = dkvx + 2048ull * 768;
      k_tfold<<<dim3(32, 24, 1), tb, 0, stream>>>(wq  + (size_t)di*768*1024, ln2w + 768ull*di, dq,               768, 1024, 0, 0, 0);
      k_tfold<<<dim3(64, 24, 1), tb, 0, stream>>>(wkv + (size_t)di*768*2048, ln2w + 768ull*di, dq + 1024ull*768, 768, 2048, 0, 0, 0);
      k_tfold<<<dim3(64, 24, 1), tb, 0, stream>>>(wkv + (size_t)di*768*2048, ln1w + 768ull*di, dkvx,             768, 2048, 0, 0, 0);
      k_tfold<<<dim3(24, 32, 1), tb, 0, stream>>>(wo  + (size_t)di*1024*768, nullptr,          dwo,             1024,  768, 0, 0, 0);
      qkvlT_p = dq; kvxT_p = dkvx; woT_p = dwo;
    }
  };
  auto ffW = [&](int d, const bf16*& w1p, const bf16*& w2p) {
    if (fullw) {
      w1p = w1T + (size_t)d * 3072 * 768;
      w2p = w2T + (size_t)d * 768 * 3072;
    } else {
      bf16* d1 = wbuf;
      bf16* d2 = wbuf + 3072ull * 768;
      k_tfold<<<dim3(96, 24, 1), tb, 0, stream>>>(ffw1 + (size_t)d*768*3072, fflnw + 768ull*d, d1,  768, 3072, 0, 0, 0);
      k_tfold<<<dim3(24, 96, 1), tb, 0, stream>>>(ffw2 + (size_t)d*3072*768, nullptr,          d2, 3072,  768, 0, 0, 0);
      w1p = d1; w2p = d2;
    }
  };

  // ---- feature projection + standardize (LN params folded into per-layer weights) ----
  for (int i = 0; i < 4; ++i) {
    int n1 = N1S[i], frd = FRDS[i];
    size_t cnt = (size_t)16 * n1 * frd;
    k_cvt<<<(int)(cnt / 1024), 256, 0, stream>>>(f_in[i], fbf[i], (int)(cnt / 4));
    for (int b0 = 0; b0 < 16; b0 += bc) {
      int rows = bc * n1;
      gemm(i == 0 ? 64 : 128, fbf[i] + (size_t)b0 * n1 * frd, pT[i], featf32,
           pb_in[i], nullptr, rows, 768, frd, false, false);
      k_std<<<rows, 256, 0, stream>>>(featf32, zfeat[i] + (size_t)b0 * n1 * 768);
    }
  }

  hipMemcpyAsync(lat, id_emb, 1024ull * 768 * 4, hipMemcpyDeviceToDevice, stream);

  // ---- depth loop ----
  for (int d = 0; d < 6; ++d) {
    for (int i = 0; i < 4; ++i) {
      int di = d * 4 + i, n1 = N1S[i];
      const bf16 *qkvlT_p, *kvxT_p, *woT_p;
      attnW(di, qkvlT_p, kvxT_p, woT_p);
      k_std<<<1024, 256, 0, stream>>>(lat, zlat);
      gemm(128, zlat, qkvlT_p, qkvl_act, qkvl_bias + 3072ull * di, nullptr,
           1024, 3072, 768, true, false);
      for (int b0 = 0; b0 < 16; b0 += bc) {
        gemm(n1 == 49 ? 64 : 128, zfeat[i] + (size_t)b0 * n1 * 768, kvxT_p, kvxbuf,
             kvx_bias + 2048ull * di, nullptr, bc * n1, 2048, 768, true, false);
        k_attn<<<bc * 16, 256, 0, stream>>>(qkvl_act, kvxbuf, attnout, n1, b0);
      }
      gemm(64, attnout, woT_p, lat, nullptr, lat, 1024, 768, 1024, false, false);
    }
    const bf16 *w1p, *w2p;
    ffW(d, w1p, w2p);
    k_std<<<1024, 256, 0, stream>>>(lat, zlat);
    gemm(128, zlat, w1p, ffh, ff_bias + 3072ull * d, nullptr, 1024, 3072, 768, true, true);
    gemm(64, ffh, w2p, lat, nullptr, lat, 1024, 768, 3072, false, false);
  }

  // ---- head ----
  k_cvt<<<768, 256, 0, stream>>>(lat, latbf, 196608);
  gemm(64, latbf, projT, headtmp, projb, nullptr, 1024, 768, 768, false, false);
  k_lnout<<<1024, 256, 0, stream>>>(headtmp, normw, normb, (float*)d_out);
}

// Round 3
// 6378.193 us; speedup vs baseline: 1.1791x; 1.1791x over previous
//
#include <hip/hip_runtime.h>
#include <hip/hip_bf16.h>
#include <cstdint>
#include <cstddef>

typedef __hip_bfloat16 bf16;
typedef float  f32x4   __attribute__((ext_vector_type(4)));
typedef float  float4v __attribute__((ext_vector_type(4)));
typedef short  short8  __attribute__((ext_vector_type(8)));
typedef short  short4v __attribute__((ext_vector_type(4)));
typedef __bf16 bf16x8  __attribute__((ext_vector_type(8)));

__device__ __forceinline__ void mfma16(f32x4& d, short8 a, short8 b) {
  d = __builtin_amdgcn_mfma_f32_16x16x32_bf16(
      __builtin_bit_cast(bf16x8, a), __builtin_bit_cast(bf16x8, b), d, 0, 0, 0);
}
__device__ __forceinline__ unsigned short f2b_bits(float x) {
  __hip_bfloat16 h = __float2bfloat16(x);
  return __builtin_bit_cast(unsigned short, h);
}
__device__ __forceinline__ float gelu_exact(float x) {
  return 0.5f * x * (1.0f + erff(x * 0.7071067811865475f));
}

// ---------- f32 -> bf16 convert, 4 elems/thread ----------
__global__ __launch_bounds__(256) void k_cvt(const float* __restrict__ src,
                                             bf16* __restrict__ dst, int n4) {
  int i = blockIdx.x * 256 + threadIdx.x;
  if (i >= n4) return;
  float4v v = *(const float4v*)(src + (size_t)i * 4);
  short4v s;
  s[0] = (short)f2b_bits(v[0]); s[1] = (short)f2b_bits(v[1]);
  s[2] = (short)f2b_bits(v[2]); s[3] = (short)f2b_bits(v[3]);
  *(short4v*)((short*)dst + (size_t)i * 4) = s;
}

// ---------- transpose (+optional per-k scale): f32 (K,N) -> bf16 (N,K) ----------
__global__ void k_tfold(const float* __restrict__ src, const float* __restrict__ scale,
                        bf16* __restrict__ dst, int K, int N,
                        long long src_bs, long long scale_bs, long long dst_bs) {
  src += (size_t)blockIdx.z * src_bs;
  dst += (size_t)blockIdx.z * dst_bs;
  const float* sc = scale ? scale + (size_t)blockIdx.z * scale_bs : nullptr;
  __shared__ float tile[32][33];
  int n0 = blockIdx.x * 32, k0 = blockIdx.y * 32;
  int tx = threadIdx.x, ty = threadIdx.y;
#pragma unroll
  for (int j = 0; j < 4; ++j) {
    int k = k0 + ty + j * 8;
    float s = sc ? sc[k] : 1.0f;
    tile[ty + j * 8][tx] = src[(size_t)k * N + n0 + tx] * s;
  }
  __syncthreads();
#pragma unroll
  for (int j = 0; j < 4; ++j) {
    int n = n0 + ty + j * 8;
    dst[(size_t)n * K + k0 + tx] = __float2bfloat16(tile[tx][ty + j * 8]);
  }
}

// ---------- bias fold: out[n] = sum_k lnb[k]*W[k][n], k-parallel ----------
__global__ __launch_bounds__(256) void k_bfold(const float* __restrict__ W,
                                               const float* __restrict__ lnb,
                                               float* __restrict__ out, int K, int N,
                                               long long w_bs, long long b_bs, long long o_bs) {
  W   += (size_t)blockIdx.y * w_bs;
  lnb += (size_t)blockIdx.y * b_bs;
  out += (size_t)blockIdx.y * o_bs;
  const int l = threadIdx.x & 63, kg = threadIdx.x >> 6;
  const int n = blockIdx.x * 64 + l;
  float a = 0.0f;
  for (int k = kg; k < K; k += 4) a = fmaf(lnb[k], W[(size_t)k * N + n], a);
  __shared__ float red[4][64];
  red[kg][l] = a;
  __syncthreads();
  if (kg == 0) out[n] = (red[0][l] + red[1][l]) + (red[2][l] + red[3][l]);
}

// ---------- row standardize (768-wide), f32 -> bf16 ----------
__global__ __launch_bounds__(256) void k_std(const float* __restrict__ src,
                                             bf16* __restrict__ dst) {
  int row = blockIdx.x;
  const float* x = src + (size_t)row * 768;
  int t = threadIdx.x;
  float a0 = x[t], a1 = x[t + 256], a2 = x[t + 512];
  float s = a0 + a1 + a2;
  float q = a0 * a0 + a1 * a1 + a2 * a2;
#pragma unroll
  for (int off = 1; off < 64; off <<= 1) { s += __shfl_xor(s, off); q += __shfl_xor(q, off); }
  __shared__ float ss[4], qs[4];
  if ((t & 63) == 0) { ss[t >> 6] = s; qs[t >> 6] = q; }
  __syncthreads();
  s = ss[0] + ss[1] + ss[2] + ss[3];
  q = qs[0] + qs[1] + qs[2] + qs[3];
  float mean = s * (1.0f / 768.0f);
  float var  = q * (1.0f / 768.0f) - mean * mean;
  float inv  = rsqrtf(var + 1e-5f);
  bf16* d = dst + (size_t)row * 768;
  d[t]       = __float2bfloat16((a0 - mean) * inv);
  d[t + 256] = __float2bfloat16((a1 - mean) * inv);
  d[t + 512] = __float2bfloat16((a2 - mean) * inv);
}

// ---------- final layernorm (768-wide) with w,b: f32 -> f32 ----------
__global__ __launch_bounds__(256) void k_lnout(const float* __restrict__ src,
                                               const float* __restrict__ w,
                                               const float* __restrict__ b,
                                               float* __restrict__ dst) {
  int row = blockIdx.x;
  const float* x = src + (size_t)row * 768;
  int t = threadIdx.x;
  float a0 = x[t], a1 = x[t + 256], a2 = x[t + 512];
  float s = a0 + a1 + a2;
  float q = a0 * a0 + a1 * a1 + a2 * a2;
#pragma unroll
  for (int off = 1; off < 64; off <<= 1) { s += __shfl_xor(s, off); q += __shfl_xor(q, off); }
  __shared__ float ss[4], qs[4];
  if ((t & 63) == 0) { ss[t >> 6] = s; qs[t >> 6] = q; }
  __syncthreads();
  s = ss[0] + ss[1] + ss[2] + ss[3];
  q = qs[0] + qs[1] + qs[2] + qs[3];
  float mean = s * (1.0f / 768.0f);
  float var  = q * (1.0f / 768.0f) - mean * mean;
  float inv  = rsqrtf(var + 1e-5f);
  float* d = dst + (size_t)row * 768;
  d[t]       = (a0 - mean) * inv * w[t]       + b[t];
  d[t + 256] = (a1 - mean) * inv * w[t + 256] + b[t + 256];
  d[t + 512] = (a2 - mean) * inv * w[t + 512] + b[t + 512];
}

// ---------- MFMA GEMM: C(M,N) = A(M,K)bf16 @ Bt(N,K)bf16 [+bias][gelu][+res f32] ----------
template <int BM, int BN, bool OBF16, bool GELU>
__global__ __launch_bounds__(256) void k_gemm(const bf16* __restrict__ A,
                                              const bf16* __restrict__ Bt,
                                              void* __restrict__ Cv,
                                              const float* __restrict__ bias,
                                              const float* __restrict__ res,
                                              int M, int N, int K) {
  constexpr int AI = BM / 32, BI = BN / 32;
  constexpr int MF = BM / 32, NF = BN / 32;
  __shared__ __align__(16) char As[BM * 128];
  __shared__ __align__(16) char Bs[BN * 128];
  const int bm = blockIdx.x * BM, bn = blockIdx.y * BN;
  const int t = threadIdx.x, lane = t & 63, w = t >> 6;
  const int wr = w >> 1, wc = w & 1;
  const int l15 = lane & 15, lg = lane >> 4;
  const int srow = t >> 3, scol = t & 7;

  const bf16* aptr[AI]; int aoff[AI];
#pragma unroll
  for (int i = 0; i < AI; ++i) {
    int r = i * 32 + srow;
    int gr = bm + r; if (gr > M - 1) gr = M - 1;
    aptr[i] = A + (size_t)gr * K + scol * 8;
    aoff[i] = r * 128 + ((scol * 16) ^ ((r & 7) << 4));
  }
  const bf16* bptr[BI]; int boff[BI];
#pragma unroll
  for (int i = 0; i < BI; ++i) {
    int r = i * 32 + srow;
    int gc = bn + r; if (gc > N - 1) gc = N - 1;
    bptr[i] = Bt + (size_t)gc * K + scol * 8;
    boff[i] = r * 128 + ((scol * 16) ^ ((r & 7) << 4));
  }

  f32x4 acc[MF][NF] = {};
  short8 av[AI], bv[BI];
#pragma unroll
  for (int i = 0; i < AI; ++i) av[i] = *(const short8*)(aptr[i]);
#pragma unroll
  for (int i = 0; i < BI; ++i) bv[i] = *(const short8*)(bptr[i]);

  const int nk = K / 64;
  for (int kt = 0; kt < nk; ++kt) {
    __syncthreads();
#pragma unroll
    for (int i = 0; i < AI; ++i) *(short8*)(As + aoff[i]) = av[i];
#pragma unroll
    for (int i = 0; i < BI; ++i) *(short8*)(Bs + boff[i]) = bv[i];
    __syncthreads();
    if (kt + 1 < nk) {
#pragma unroll
      for (int i = 0; i < AI; ++i) av[i] = *(const short8*)(aptr[i] + (size_t)(kt + 1) * 64);
#pragma unroll
      for (int i = 0; i < BI; ++i) bv[i] = *(const short8*)(bptr[i] + (size_t)(kt + 1) * 64);
    }
#pragma unroll
    for (int ks = 0; ks < 2; ++ks) {
      short8 af[MF], bfr[NF];
#pragma unroll
      for (int m = 0; m < MF; ++m) {
        int r = wr * (BM / 2) + m * 16 + l15;
        af[m] = *(const short8*)(As + r * 128 + ((ks * 64 + lg * 16) ^ ((r & 7) << 4)));
      }
#pragma unroll
      for (int n = 0; n < NF; ++n) {
        int r = wc * (BN / 2) + n * 16 + l15;
        bfr[n] = *(const short8*)(Bs + r * 128 + ((ks * 64 + lg * 16) ^ ((r & 7) << 4)));
      }
#pragma unroll
      for (int m = 0; m < MF; ++m)
#pragma unroll
        for (int n = 0; n < NF; ++n) mfma16(acc[m][n], af[m], bfr[n]);
    }
  }
#pragma unroll
  for (int m = 0; m < MF; ++m) {
    int gr0 = bm + wr * (BM / 2) + m * 16 + lg * 4;
#pragma unroll
    for (int n = 0; n < NF; ++n) {
      int gc = bn + wc * (BN / 2) + n * 16 + l15;
      float bvs = bias ? bias[gc] : 0.0f;
#pragma unroll
      for (int r = 0; r < 4; ++r) {
        int gr = gr0 + r;
        if (gr < M) {
          float v = acc[m][n][r] + bvs;
          if (GELU) v = gelu_exact(v);
          if (res) v += res[(size_t)gr * N + gc];
          if (OBF16) ((bf16*)Cv)[(size_t)gr * N + gc] = __float2bfloat16(v);
          else       ((float*)Cv)[(size_t)gr * N + gc] = v;
        }
      }
    }
  }
}

// ---------- fused attention: one block per (local b, h); 4 waves, 16 q-rows each ----------
__global__ __launch_bounds__(256) void k_attn(const bf16* __restrict__ qkvl,
                                              const bf16* __restrict__ kvx,
                                              bf16* __restrict__ outp, int n1, int b0) {
  const int bh = blockIdx.x;
  const int bl = bh >> 4, h = bh & 15;
  const int b = b0 + bl;
  __shared__ __align__(16) char Qs[64 * 128];
  __shared__ __align__(16) char Ks[64 * 128];
  __shared__ __align__(16) char Vt[64 * 128];
  __shared__ __align__(16) char Ps[4][16 * 128];
  const int t = threadIdx.x, lane = t & 63, w = t >> 6;
  const int l15 = lane & 15, lg = lane >> 4;

#pragma unroll
  for (int it = 0; it < 2; ++it) {
    int slot = it * 256 + t; int r = slot >> 3, c = slot & 7;
    short8 v = *(const short8*)(qkvl + (size_t)(b * 64 + r) * 3072 + h * 64 + c * 8);
    *(short8*)(Qs + r * 128 + ((c * 16) ^ ((r & 7) << 4))) = v;
  }
  const int n_kv = n1 + 64;
  const int nch = (n_kv + 63) >> 6;
  float m_run[4], l_run[4];
  f32x4 o[4] = {};
#pragma unroll
  for (int r = 0; r < 4; ++r) { m_run[r] = -1e30f; l_run[r] = 0.0f; }

  short8 kreg[2], vreg[2];
  auto loadKV = [&](int ch) {
#pragma unroll
    for (int it = 0; it < 2; ++it) {
      int slot = it * 256 + t; int rr = slot >> 3, c = slot & 7;
      int j = ch * 64 + rr;
      short8 kv = {}; short8 vv = {};
      if (j < n_kv) {
        const bf16* kb;
        if (j < n1) kb = kvx + (size_t)(bl * n1 + j) * 2048 + h * 64;
        else        kb = qkvl + (size_t)(b * 64 + (j - n1)) * 3072 + 1024 + h * 64;
        kv = *(const short8*)(kb + c * 8);
        vv = *(const short8*)(kb + 1024 + c * 8);
      }
      kreg[it] = kv; vreg[it] = vv;
    }
  };
  loadKV(0);

  for (int ch = 0; ch < nch; ++ch) {
    __syncthreads();
#pragma unroll
    for (int it = 0; it < 2; ++it) {
      int slot = it * 256 + t; int rr = slot >> 3, c = slot & 7;
      *(short8*)(Ks + rr * 128 + ((c * 16) ^ ((rr & 7) << 4))) = kreg[it];
#pragma unroll
      for (int j2 = 0; j2 < 8; ++j2) {
        int dh = c * 8 + j2;
        *(short*)(Vt + dh * 128 + ((rr * 2) ^ ((dh & 7) << 4))) = vreg[it][j2];
      }
    }
    __syncthreads();
    if (ch + 1 < nch) loadKV(ch + 1);

    f32x4 s[4] = {};
#pragma unroll
    for (int ks = 0; ks < 2; ++ks) {
      int qr = w * 16 + l15;
      short8 qf = *(const short8*)(Qs + qr * 128 + ((ks * 64 + lg * 16) ^ ((qr & 7) << 4)));
#pragma unroll
      for (int n = 0; n < 4; ++n) {
        int kr = n * 16 + l15;
        short8 kf = *(const short8*)(Ks + kr * 128 + ((ks * 64 + lg * 16) ^ ((kr & 7) << 4)));
        mfma16(s[n], qf, kf);
      }
    }
    float p[4][4];
#pragma unroll
    for (int r = 0; r < 4; ++r) {
      float mx = m_run[r];
#pragma unroll
      for (int n = 0; n < 4; ++n) {
        float v = s[n][r] * 0.125f;
        int kvi = ch * 64 + n * 16 + l15;
        if (kvi >= n_kv) v = -1e30f;
        s[n][r] = v;
        mx = fmaxf(mx, v);
      }
#pragma unroll
      for (int off = 1; off < 16; off <<= 1) mx = fmaxf(mx, __shfl_xor(mx, off));
      float scl = __expf(m_run[r] - mx);
      m_run[r] = mx;
      float rs = 0.0f;
#pragma unroll
      for (int n = 0; n < 4; ++n) { float pv = __expf(s[n][r] - mx); p[n][r] = pv; rs += pv; }
#pragma unroll
      for (int off = 1; off < 16; off <<= 1) rs += __shfl_xor(rs, off);
      l_run[r] = l_run[r] * scl + rs;
#pragma unroll
      for (int nn = 0; nn < 4; ++nn) o[nn][r] *= scl;
    }
#pragma unroll
    for (int n = 0; n < 4; ++n)
#pragma unroll
      for (int r = 0; r < 4; ++r) {
        int q = lg * 4 + r; int kv = n * 16 + l15;
        *(unsigned short*)(Ps[w] + q * 128 + ((kv * 2) ^ ((q & 7) << 4))) = f2b_bits(p[n][r]);
      }
#pragma unroll
    for (int ks = 0; ks < 2; ++ks) {
      short8 pf = *(const short8*)(Ps[w] + l15 * 128 + ((ks * 64 + lg * 16) ^ ((l15 & 7) << 4)));
#pragma unroll
      for (int nn = 0; nn < 4; ++nn) {
        int dh = nn * 16 + l15;
        short8 vf = *(const short8*)(Vt + dh * 128 + ((ks * 64 + lg * 16) ^ ((dh & 7) << 4)));
        mfma16(o[nn], pf, vf);
      }
    }
  }
#pragma unroll
  for (int nn = 0; nn < 4; ++nn)
#pragma unroll
    for (int r = 0; r < 4; ++r) {
      int qr = w * 16 + lg * 4 + r;
      int dh = nn * 16 + l15;
      float v = o[nn][r] / l_run[r];
      outp[(size_t)(b * 64 + qr) * 1024 + h * 64 + dh] = __float2bfloat16(v);
    }
}

// =========================== host ===========================
extern "C" void kernel_launch(void* const* d_in, const int* in_sizes, int n_in,
                              void* d_out, int out_size, void* d_ws, size_t ws_size,
                              hipStream_t stream) {
  (void)in_sizes; (void)n_in; (void)out_size;
  const float* id_emb = (const float*)d_in[0];
  const float* f_in[4]  = {(const float*)d_in[4],  (const float*)d_in[3],
                           (const float*)d_in[2],  (const float*)d_in[1]};
  const float* pw_in[4] = {(const float*)d_in[11], (const float*)d_in[9],
                           (const float*)d_in[7],  (const float*)d_in[5]};
  const float* pb_in[4] = {(const float*)d_in[12], (const float*)d_in[10],
                           (const float*)d_in[8],  (const float*)d_in[6]};
  const float* ln1w = (const float*)d_in[13];
  const float* ln1b = (const float*)d_in[14];
  const float* ln2w = (const float*)d_in[15];
  const float* ln2b = (const float*)d_in[16];
  const float* wq   = (const float*)d_in[17];
  const float* wkv  = (const float*)d_in[18];
  const float* wo   = (const float*)d_in[19];
  const float* fflnw = (const float*)d_in[20];
  const float* fflnb = (const float*)d_in[21];
  const float* ffw1  = (const float*)d_in[22];
  const float* ffw2  = (const float*)d_in[23];
  const float* projw = (const float*)d_in[24];
  const float* projb = (const float*)d_in[25];
  const float* normw = (const float*)d_in[26];
  const float* normb = (const float*)d_in[27];

  static const int N1S[4]  = {49, 196, 784, 3136};
  static const int FRDS[4] = {512, 256, 128, 64};

  // ---- adaptive workspace plan (ws_size is fixed per run -> deterministic) ----
  bf16 *zfeat[4], *fbf[4], *pT[4], *projT;
  float *qkvl_bias, *kvx_bias, *ff_bias, *lat, *headtmp;
  bf16 *qkvl_act, *attnout, *zlat, *latbf, *ffh;
  bf16 *wqkvlT = nullptr, *wkvxT = nullptr, *woT = nullptr, *w1T = nullptr, *w2T = nullptr;
  bf16 *wbuf = nullptr;
  char *big;

  auto assign = [&](bool fullw, int bc) -> size_t {
    size_t off = 0; char* base = (char*)d_ws;
    auto A = [&](size_t b) -> char* {
      char* p = base + off; off = (off + b + 255) & ~(size_t)255; return p;
    };
    for (int i = 0; i < 4; ++i) zfeat[i] = (bf16*)A((size_t)16 * N1S[i] * 768 * 2);
    for (int i = 0; i < 4; ++i) fbf[i]   = (bf16*)A((size_t)16 * N1S[i] * FRDS[i] * 2);
    for (int i = 0; i < 4; ++i) pT[i]    = (bf16*)A((size_t)768 * FRDS[i] * 2);
    projT     = (bf16*)A(768ull * 768 * 2);
    qkvl_bias = (float*)A(24ull * 3072 * 4);
    kvx_bias  = (float*)A(24ull * 2048 * 4);
    ff_bias   = (float*)A(6ull * 3072 * 4);
    qkvl_act  = (bf16*)A(1024ull * 3072 * 2);
    attnout   = (bf16*)A(1024ull * 1024 * 2);
    lat       = (float*)A(1024ull * 768 * 4);
    zlat      = (bf16*)A(1024ull * 768 * 2);
    if (fullw) {
      wqkvlT = (bf16*)A(24ull * 3072 * 768 * 2);
      wkvxT  = (bf16*)A(24ull * 2048 * 768 * 2);
      woT    = (bf16*)A(24ull * 768 * 1024 * 2);
      w1T    = (bf16*)A(6ull * 3072 * 768 * 2);
      w2T    = (bf16*)A(6ull * 768 * 3072 * 2);
      wbuf = nullptr;
    } else {
      wbuf = (bf16*)A(((3072ull + 2048) * 768 + 768ull * 1024) * 2);
      wqkvlT = wkvxT = woT = w1T = w2T = nullptr;
    }
    big = A((size_t)bc * 3136 * 2048 * 2);
    ffh = qkvl_act; headtmp = (float*)qkvl_act; latbf = zlat;
    return off;
  };

  static const bool FULLS[10] = {true,true,true,false,false,true,true,false,false,false};
  static const int  BCS[10]   = {16,  8,   4,   16,   8,    2,   1,   4,    2,    1};
  bool fullw = false; int bc = 1; bool ok = false;
  for (int c = 0; c < 10; ++c) {
    if (assign(FULLS[c], BCS[c]) <= ws_size) { fullw = FULLS[c]; bc = BCS[c]; ok = true; break; }
  }
  if (!ok) return;

  float* featf32 = (float*)big;
  bf16*  kvxbuf  = (bf16*)big;

  auto gemm = [&](int tile, const bf16* A, const bf16* Bt, void* C,
                  const float* bias, const float* res, int M, int N, int K,
                  bool obf, bool gl) {
    if (tile == 128) {
      dim3 g((M + 127) / 128, N / 128);
      if (obf && gl) k_gemm<128,128,true ,true ><<<g,256,0,stream>>>(A,Bt,C,bias,res,M,N,K);
      else if (obf)  k_gemm<128,128,true ,false><<<g,256,0,stream>>>(A,Bt,C,bias,res,M,N,K);
      else           k_gemm<128,128,false,false><<<g,256,0,stream>>>(A,Bt,C,bias,res,M,N,K);
    } else {
      dim3 g((M + 63) / 64, N / 64);
      if (obf && gl)  k_gemm<64,64,true ,true ><<<g,256,0,stream>>>(A,Bt,C,bias,res,M,N,K);
      else if (obf)   k_gemm<64,64,true ,false><<<g,256,0,stream>>>(A,Bt,C,bias,res,M,N,K);
      else            k_gemm<64,64,false,false><<<g,256,0,stream>>>(A,Bt,C,bias,res,M,N,K);
    }
  };
  auto pick = [&](int M) -> int { return M >= 2048 ? 128 : 64; };

  dim3 tb(32, 8);

  // ---- bias folds (k-parallel GEMV) ----
  k_bfold<<<dim3(16, 24), 256, 0, stream>>>(wq,  ln2b, qkvl_bias,        768, 1024, 768LL*1024, 768, 3072);
  k_bfold<<<dim3(32, 24), 256, 0, stream>>>(wkv, ln2b, qkvl_bias + 1024, 768, 2048, 768LL*2048, 768, 3072);
  k_bfold<<<dim3(32, 24), 256, 0, stream>>>(wkv, ln1b, kvx_bias,         768, 2048, 768LL*2048, 768, 2048);
  k_bfold<<<dim3(48, 6),  256, 0, stream>>>(ffw1, fflnb, ff_bias,        768, 3072, 768LL*3072, 768, 3072);

  // ---- small folded weights (always) ----
  for (int i = 0; i < 4; ++i)
    k_tfold<<<dim3(24, FRDS[i] / 32, 1), tb, 0, stream>>>(pw_in[i], nullptr, pT[i], FRDS[i], 768, 0, 0, 0);
  k_tfold<<<dim3(24, 24, 1), tb, 0, stream>>>(projw, nullptr, projT, 768, 768, 0, 0, 0);

  // ---- full-mode weight folds (batched over layers) ----
  if (fullw) {
    k_tfold<<<dim3(32, 24, 24), tb, 0, stream>>>(wq,  ln2w, wqkvlT,              768, 1024, 768LL*1024, 768, 3072LL*768);
    k_tfold<<<dim3(64, 24, 24), tb, 0, stream>>>(wkv, ln2w, wqkvlT + 1024LL*768, 768, 2048, 768LL*2048, 768, 3072LL*768);
    k_tfold<<<dim3(64, 24, 24), tb, 0, stream>>>(wkv, ln1w, wkvxT,               768, 2048, 768LL*2048, 768, 2048LL*768);
    k_tfold<<<dim3(24, 32, 24), tb, 0, stream>>>(wo,  nullptr, woT,             1024,  768, 1024LL*768,   0,  768LL*1024);
    k_tfold<<<dim3(96, 24, 6),  tb, 0, stream>>>(ffw1, fflnw, w1T,               768, 3072, 768LL*3072, 768, 3072LL*768);
    k_tfold<<<dim3(24, 96, 6),  tb, 0, stream>>>(ffw2, nullptr, w2T,            3072,  768, 3072LL*768,   0,  768LL*3072);
  }

  auto attnW = [&](int di, const bf16*& qkvlT_p, const bf16*& kvxT_p, const bf16*& woT_p) {
    if (fullw) {
      qkvlT_p = wqkvlT + (size_t)di * 3072 * 768;
      kvxT_p  = wkvxT  + (size_t)di * 2048 * 768;
      woT_p   = woT    + (size_t)di * 768 * 1024;
    } else {
      bf16* dq   = wbuf;
      bf16* dkvx = wbuf + 3072ull * 768;
      bf16* dwo  = dkvx + 2048ull * 768;
      k_tfold<<<dim3(32, 24, 1), tb, 0, stream>>>(wq  + (size_t)di*768*1024, ln2w + 768ull*di, dq,               768, 1024, 0, 0, 0);
      k_tfold<<<dim3(64, 24, 1), tb, 0, stream>>>(wkv + (size_t)di*768*2048, ln2w + 768ull*di, dq + 1024ull*768, 768, 2048, 0, 0, 0);
      k_tfold<<<dim3(64, 24, 1), tb, 0, stream>>>(wkv + (size_t)di*768*2048, ln1w + 768ull*di, dkvx,             768, 2048, 0, 0, 0);
      k_tfold<<<dim3(24, 32, 1), tb, 0, stream>>>(wo  + (size_t)di*1024*768, nullptr,          dwo,             1024,  768, 0, 0, 0);
      qkvlT_p = dq; kvxT_p = dkvx; woT_p = dwo;
    }
  };
  auto ffW = [&](int d, const bf16*& w1p, const bf16*& w2p) {
    if (fullw) {
      w1p = w1T + (size_t)d * 3072 * 768;
      w2p = w2T + (size_t)d * 768 * 3072;
    } else {
      bf16* d1 = wbuf;
      bf16* d2 = wbuf + 3072ull * 768;
      k_tfold<<<dim3(96, 24, 1), tb, 0, stream>>>(ffw1 + (size_t)d*768*3072, fflnw + 768ull*d, d1,  768, 3072, 0, 0, 0);
      k_tfold<<<dim3(24, 96, 1), tb, 0, stream>>>(ffw2 + (size_t)d*3072*768, nullptr,          d2, 3072,  768, 0, 0, 0);
      w1p = d1; w2p = d2;
    }
  };

  // ---- feature projection + standardize (LN params folded into per-layer weights) ----
  for (int i = 0; i < 4; ++i) {
    int n1 = N1S[i], frd = FRDS[i];
    size_t cnt = (size_t)16 * n1 * frd;
    k_cvt<<<(int)(cnt / 1024), 256, 0, stream>>>(f_in[i], fbf[i], (int)(cnt / 4));
    for (int b0 = 0; b0 < 16; b0 += bc) {
      int rows = bc * n1;
      gemm(pick(rows), fbf[i] + (size_t)b0 * n1 * frd, pT[i], featf32,
           pb_in[i], nullptr, rows, 768, frd, false, false);
      k_std<<<rows, 256, 0, stream>>>(featf32, zfeat[i] + (size_t)b0 * n1 * 768);
    }
  }

  hipMemcpyAsync(lat, id_emb, 1024ull * 768 * 4, hipMemcpyDeviceToDevice, stream);

  // ---- depth loop ----
  for (int d = 0; d < 6; ++d) {
    for (int i = 0; i < 4; ++i) {
      int di = d * 4 + i, n1 = N1S[i];
      const bf16 *qkvlT_p, *kvxT_p, *woT_p;
      attnW(di, qkvlT_p, kvxT_p, woT_p);
      k_std<<<1024, 256, 0, stream>>>(lat, zlat);
      gemm(64, zlat, qkvlT_p, qkvl_act, qkvl_bias + 3072ull * di, nullptr,
           1024, 3072, 768, true, false);
      for (int b0 = 0; b0 < 16; b0 += bc) {
        int rows = bc * n1;
        gemm(pick(rows), zfeat[i] + (size_t)b0 * n1 * 768, kvxT_p, kvxbuf,
             kvx_bias + 2048ull * di, nullptr, rows, 2048, 768, true, false);
        k_attn<<<bc * 16, 256, 0, stream>>>(qkvl_act, kvxbuf, attnout, n1, b0);
      }
      gemm(64, attnout, woT_p, lat, nullptr, lat, 1024, 768, 1024, false, false);
    }
    const bf16 *w1p, *w2p;
    ffW(d, w1p, w2p);
    k_std<<<1024, 256, 0, stream>>>(lat, zlat);
    gemm(64, zlat, w1p, ffh, ff_bias + 3072ull * d, nullptr, 1024, 3072, 768, true, true);
    gemm(64, ffh, w2p, lat, nullptr, lat, 1024, 768, 3072, false, false);
  }

  // ---- head ----
  k_cvt<<<768, 256, 0, stream>>>(lat, latbf, 196608);
  gemm(64, latbf, projT, headtmp, projb, nullptr, 1024, 768, 768, false, false);
  k_lnout<<<1024, 256, 0, stream>>>(headtmp, normw, normb, (float*)d_out);
}